// Round 10
// baseline (214.139 us; speedup 1.0000x reference)
//
#include <hip/hip_runtime.h>

#define BB 4096
#define TT 512
#define HH 32

typedef _Float16 half8 __attribute__((ext_vector_type(8)));  // MFMA A/B frag (4 VGPRs)
typedef _Float16 h2    __attribute__((ext_vector_type(2)));  // packed f16 pair
typedef float    f32x4 __attribute__((ext_vector_type(4)));  // MFMA C/D

#define MFMA16F(a, b, c) __builtin_amdgcn_mfma_f32_16x16x32_f16((a), (b), (c), 0, 0, 0)

union frag_u { half8 h8; h2 p[4]; };

__device__ __forceinline__ h2 pkrtz(float a, float b) {
    auto r = __builtin_amdgcn_cvt_pkrtz(a, b);
    union { decltype(r) i; h2 o; } u;
    u.i = r;
    return u.o;
}

// tanh(v) ~= v * P(v^2), P quintic on |v|<=2.75 (max err ~2e-3).
// EXACT round-0 builtin version.
__device__ __forceinline__ h2 tanh_h2(h2 v) {
    const h2 LO = {(_Float16)(-2.75f), (_Float16)(-2.75f)};
    const h2 HI = {(_Float16)(2.75f), (_Float16)(2.75f)};
    const h2 C0 = {(_Float16)(0.9976293f), (_Float16)(0.9976293f)};
    const h2 C1 = {(_Float16)(-0.3098016f), (_Float16)(-0.3098016f)};
    const h2 C2 = {(_Float16)(0.0889744f), (_Float16)(0.0889744f)};
    const h2 C3 = {(_Float16)(-0.0163448f), (_Float16)(-0.0163448f)};
    const h2 C4 = {(_Float16)(0.0016113f), (_Float16)(0.0016113f)};
    const h2 C5 = {(_Float16)(-0.00006405f), (_Float16)(-0.00006405f)};
    v = __builtin_elementwise_min(v, HI);
    v = __builtin_elementwise_max(v, LO);
    h2 u = v * v;
    h2 t = __builtin_elementwise_fma(u, C5, C4);
    t = __builtin_elementwise_fma(u, t, C3);
    t = __builtin_elementwise_fma(u, t, C2);
    t = __builtin_elementwise_fma(u, t, C1);
    t = __builtin_elementwise_fma(u, t, C0);
    return v * t;
}

// SINGLE-WAVE, CHAIN-SHORTENED (lag-2) kernel.
// Round 4-9 calibration: MFMA dependent latency ~250 cy at 1-2 waves/SIMD.
// R0's h1 recurrence had TWO dependent MFMAs per step (dbp = Whh1.h1 + b1,
// then d10 = Wih1.h0 + dbp consumes dbp as SrcC) -> 545-cy cycle -> 750
// measured.  Reassociation: e = Wih1.h0 + b1 (h0 is OFF the h1 cycle), then
// d1 = Whh1.h1 + e -> each recurrence cycle carries ONE MFMA + tanh (~295 cy).
// Layer-1 lags 2 steps so e (computed from h0(s-2) during iter s-1) is ready
// at iter-s entry: ALL SIX MFMAs' operands are ready at step entry.
// No LDS, no barriers.  f32 add-reassociation only (b1 folded into e);
// everything else matches the verified round-0 arithmetic.
__global__ __launch_bounds__(64) void rnn2_mfma_lag2(
    const float* __restrict__ x,      // [B, T]
    const float* __restrict__ hstate, // [2, B, H]
    const float* __restrict__ Wih0,   // [H, 1]
    const float* __restrict__ Whh0,   // [H, H]
    const float* __restrict__ bih0,   // [H]
    const float* __restrict__ bhh0,   // [H]
    const float* __restrict__ Wih1,   // [H, H]
    const float* __restrict__ Whh1,   // [H, H]
    const float* __restrict__ bih1,   // [H]
    const float* __restrict__ bhh1,   // [H]
    const float* __restrict__ Wfc,    // [1, H]
    const float* __restrict__ bfc,    // [1]
    float* __restrict__ out)          // [B] pred ++ [2,B,H] h_new
{
    const int l = threadIdx.x;   // 0..63
    const int q = l >> 4;        // lane quad -> k-offset 8q
    const int n = l & 15;        // batch-in-tile / matrix row m
    const int b = blockIdx.x * 16 + n;

    // ---- weight A-fragments (f16), permuted rows (round-0 exact) ----
    const int r0 = 8 * (n >> 2) + (n & 3);
    half8 A0[2], A1i[2], A1h[2];
#pragma unroll
    for (int t = 0; t < 2; ++t) {
        const int row = r0 + 4 * t;
        const float* p0 = Whh0 + row * HH + q * 8;
        const float* p1 = Wih1 + row * HH + q * 8;
        const float* p2 = Whh1 + row * HH + q * 8;
        frag_u f0, f1, f2;
#pragma unroll
        for (int jj = 0; jj < 4; ++jj) {
            f0.p[jj] = h2{(_Float16)p0[2 * jj], (_Float16)p0[2 * jj + 1]};
            f1.p[jj] = h2{(_Float16)p1[2 * jj], (_Float16)p1[2 * jj + 1]};
            f2.p[jj] = h2{(_Float16)p2[2 * jj], (_Float16)p2[2 * jj + 1]};
        }
        A0[t] = f0.h8; A1i[t] = f1.h8; A1h[t] = f2.h8;
    }

    // ---- per-lane constants over j=0..7 (h' = 8q + j) ----
    float wxs[8], b0s[8], wfc8[8];
#pragma unroll
    for (int j = 0; j < 8; ++j) {
        const int hh = 8 * q + j;
        wxs[j]  = Wih0[hh];
        b0s[j]  = bih0[hh] + bhh0[hh];
        wfc8[j] = Wfc[hh];
    }
    f32x4 c1t0, c1t1;                 // layer-1 bias (goes into e now)
#pragma unroll
    for (int r = 0; r < 4; ++r) {
        c1t0[r] = bih1[8 * q + r] + bhh1[8 * q + r];
        c1t1[r] = bih1[8 * q + 4 + r] + bhh1[8 * q + 4 + r];
    }

    // ---- initial h states ----
    frag_u hb0, hb1;
    {
        const float* p0 = hstate + (size_t)b * HH + 8 * q;
        const float* p1 = hstate + (size_t)BB * HH + (size_t)b * HH + 8 * q;
#pragma unroll
        for (int jj = 0; jj < 4; ++jj) {
            hb0.p[jj] = h2{(_Float16)p0[2 * jj], (_Float16)p0[2 * jj + 1]};
            hb1.p[jj] = h2{(_Float16)p1[2 * jj], (_Float16)p1[2 * jj + 1]};
        }
    }

    const float4* xp = (const float4*)(x + (size_t)b * TT);
    float4 xc = xp[0];

    f32x4 e0p, e1p;    // e = Wih1 . h0(s-2) + b1, ready for this iter's d1

    // ---- iter 0 (s=0): layer-0 only -> h0(0) ----
    {
        f32x4 c00, c01;
#pragma unroll
        for (int r = 0; r < 4; ++r) {
            c00[r] = fmaf(wxs[r], xc.x, b0s[r]);
            c01[r] = fmaf(wxs[4 + r], xc.x, b0s[4 + r]);
        }
        f32x4 d00 = MFMA16F(A0[0], hb0.h8, c00);
        f32x4 d01 = MFMA16F(A0[1], hb0.h8, c01);
        hb0.p[0] = tanh_h2(pkrtz(d00[0], d00[1]));
        hb0.p[1] = tanh_h2(pkrtz(d00[2], d00[3]));
        hb0.p[2] = tanh_h2(pkrtz(d01[0], d01[1]));
        hb0.p[3] = tanh_h2(pkrtz(d01[2], d01[3]));
    }
    // ---- iter 1 (s=1): e from h0(0); layer-0 -> h0(1) ----
    {
        e0p = MFMA16F(A1i[0], hb0.h8, c1t0);
        e1p = MFMA16F(A1i[1], hb0.h8, c1t1);
        f32x4 c00, c01;
#pragma unroll
        for (int r = 0; r < 4; ++r) {
            c00[r] = fmaf(wxs[r], xc.y, b0s[r]);
            c01[r] = fmaf(wxs[4 + r], xc.y, b0s[4 + r]);
        }
        f32x4 d00 = MFMA16F(A0[0], hb0.h8, c00);
        f32x4 d01 = MFMA16F(A0[1], hb0.h8, c01);
        hb0.p[0] = tanh_h2(pkrtz(d00[0], d00[1]));
        hb0.p[1] = tanh_h2(pkrtz(d00[2], d00[3]));
        hb0.p[2] = tanh_h2(pkrtz(d01[0], d01[1]));
        hb0.p[3] = tanh_h2(pkrtz(d01[2], d01[3]));
    }

    // Iter s (s>=2).  Entry: hb0 = h0(s-1), hb1 = h1(s-3),
    //   e_p = Wih1.h0(s-2) + b1.   All six MFMA operands ready at entry.
    // Computes: h1(s-2) (one MFMA on the h1 cycle), h0(s), and
    //   e_n = Wih1.h0(s-1) + b1 for the next iter.
#define STEP(XT)                                                              \
    {                                                                         \
        f32x4 d10 = MFMA16F(A1h[0], hb1.h8, e0p);                             \
        f32x4 d11 = MFMA16F(A1h[1], hb1.h8, e1p);                             \
        f32x4 en0 = MFMA16F(A1i[0], hb0.h8, c1t0);                            \
        f32x4 en1 = MFMA16F(A1i[1], hb0.h8, c1t1);                            \
        f32x4 c00, c01;                                                       \
        _Pragma("unroll")                                                     \
        for (int r = 0; r < 4; ++r) {                                         \
            c00[r] = fmaf(wxs[r], (XT), b0s[r]);                              \
            c01[r] = fmaf(wxs[4 + r], (XT), b0s[4 + r]);                      \
        }                                                                     \
        f32x4 d00 = MFMA16F(A0[0], hb0.h8, c00);                              \
        f32x4 d01 = MFMA16F(A0[1], hb0.h8, c01);                              \
        hb1.p[0] = tanh_h2(pkrtz(d10[0], d10[1]));                            \
        hb1.p[1] = tanh_h2(pkrtz(d10[2], d10[3]));                            \
        hb1.p[2] = tanh_h2(pkrtz(d11[0], d11[1]));                            \
        hb1.p[3] = tanh_h2(pkrtz(d11[2], d11[3]));                            \
        hb0.p[0] = tanh_h2(pkrtz(d00[0], d00[1]));                            \
        hb0.p[1] = tanh_h2(pkrtz(d00[2], d00[3]));                            \
        hb0.p[2] = tanh_h2(pkrtz(d01[0], d01[1]));                            \
        hb0.p[3] = tanh_h2(pkrtz(d01[2], d01[3]));                            \
        e0p = en0; e1p = en1;                                                 \
    }

    // main loop: k = 0..126 handles s = 4k+2 .. 4k+5
    for (int k = 0; k < TT / 4 - 1; ++k) {
        float4 xn = xp[k + 1];
        STEP(xc.z);
        STEP(xc.w);
        STEP(xn.x);
        STEP(xn.y);
        xc = xn;
    }
    // s = 510, 511  (xc = xp[127])
    STEP(xc.z);
    STEP(xc.w);
    // exit: hb0 = h0(511), hb1 = h1(509), e_p = Wih1.h0(510) + b1

    // ---- drain: h1(510), then h1(511) ----
    {
        f32x4 d10 = MFMA16F(A1h[0], hb1.h8, e0p);
        f32x4 d11 = MFMA16F(A1h[1], hb1.h8, e1p);
        f32x4 en0 = MFMA16F(A1i[0], hb0.h8, c1t0);   // Wih1.h0(511) + b1
        f32x4 en1 = MFMA16F(A1i[1], hb0.h8, c1t1);
        hb1.p[0] = tanh_h2(pkrtz(d10[0], d10[1]));
        hb1.p[1] = tanh_h2(pkrtz(d10[2], d10[3]));
        hb1.p[2] = tanh_h2(pkrtz(d11[0], d11[1]));
        hb1.p[3] = tanh_h2(pkrtz(d11[2], d11[3]));   // h1(510)
        e0p = en0; e1p = en1;
    }
    {
        f32x4 d10 = MFMA16F(A1h[0], hb1.h8, e0p);
        f32x4 d11 = MFMA16F(A1h[1], hb1.h8, e1p);
        hb1.p[0] = tanh_h2(pkrtz(d10[0], d10[1]));
        hb1.p[1] = tanh_h2(pkrtz(d10[2], d10[3]));
        hb1.p[2] = tanh_h2(pkrtz(d11[0], d11[1]));
        hb1.p[3] = tanh_h2(pkrtz(d11[2], d11[3]));   // h1(511)
    }

    // ---- epilogue (round-0 exact) ----
    float hf0[8], hf1[8];
#pragma unroll
    for (int jj = 0; jj < 4; ++jj) {
        hf0[2 * jj]     = (float)hb0.p[jj].x;
        hf0[2 * jj + 1] = (float)hb0.p[jj].y;
        hf1[2 * jj]     = (float)hb1.p[jj].x;
        hf1[2 * jj + 1] = (float)hb1.p[jj].y;
    }
    float p = 0.f;
#pragma unroll
    for (int j = 0; j < 8; ++j) p = fmaf(wfc8[j], hf1[j], p);
    p += __shfl_xor(p, 16);
    p += __shfl_xor(p, 32);
    if (q == 0) out[b] = p + bfc[0];

#pragma unroll
    for (int j = 0; j < 8; ++j) {
        out[BB + (size_t)b * HH + 8 * q + j]                  = hf0[j];
        out[BB + (size_t)BB * HH + (size_t)b * HH + 8 * q + j] = hf1[j];
    }
}

extern "C" void kernel_launch(void* const* d_in, const int* in_sizes, int n_in,
                              void* d_out, int out_size, void* d_ws, size_t ws_size,
                              hipStream_t stream) {
    const float* x      = (const float*)d_in[0];
    const float* hstate = (const float*)d_in[1];
    const float* Wih0   = (const float*)d_in[2];
    const float* Whh0   = (const float*)d_in[3];
    const float* bih0   = (const float*)d_in[4];
    const float* bhh0   = (const float*)d_in[5];
    const float* Wih1   = (const float*)d_in[6];
    const float* Whh1   = (const float*)d_in[7];
    const float* bih1   = (const float*)d_in[8];
    const float* bhh1   = (const float*)d_in[9];
    const float* Wfc    = (const float*)d_in[10];
    const float* bfc    = (const float*)d_in[11];
    float* out = (float*)d_out;

    dim3 grid(BB / 16);  // 256 blocks x 1 wave, one 16-batch tile each
    dim3 block(64);
    hipLaunchKernelGGL(rnn2_mfma_lag2, grid, block, 0, stream,
                       x, hstate, Wih0, Whh0, bih0, bhh0,
                       Wih1, Whh1, bih1, bhh1, Wfc, bfc, out);
}